// Round 17
// baseline (159.791 us; speedup 1.0000x reference)
//
#include <hip/hip_runtime.h>
#include <stdint.h>

#define SEQLEN 4096
#define DMODEL 1024
#define NHEADS 16
#define DKDIM  64

typedef unsigned short u16;
typedef unsigned int   u32;
using f32x4 = __attribute__((ext_vector_type(4))) float;
using i32x4 = __attribute__((ext_vector_type(4))) int;
using i32x2 = __attribute__((ext_vector_type(2))) int;
using u16x8 = __attribute__((ext_vector_type(8))) unsigned short;

__device__ __forceinline__ u16 f2bf(float f) {
    u32 x = __builtin_bit_cast(u32, f);
    u32 r = x + 0x7fffu + ((x >> 16) & 1u);   // RNE
    return (u16)(r >> 16);
}
__device__ __forceinline__ float exp2a(float x) {
    float r; asm("v_exp_f32 %0, %1" : "=v"(r) : "v"(x)); return r;
}
__device__ __forceinline__ u32 cvtpk(float lo, float hi) {
    u32 r; asm("v_cvt_pk_bf16_f32 %0, %1, %2" : "=v"(r) : "v"(lo), "v"(hi)); return r;
}

// 16x16x32: A lane holds A[lane&15][(lane>>4)*8+j]; B: B[(lane>>4)*8+j][lane&15];
// C/D: D[(lane>>4)*4+r][lane&15]
__device__ __forceinline__ void mfma_bf16(f32x4& d, i32x4 a, i32x4 b) {
    asm("v_mfma_f32_16x16x32_bf16 %0, %1, %2, %0" : "+v"(d) : "v"(a), "v"(b));
}
// 16x16x16: A lane holds A[lane&15][(lane>>4)*4+j]; B: B[(lane>>4)*4+j][lane&15]
__device__ __forceinline__ void mfma16_bf16(f32x4& d, i32x2 a, i32x2 b) {
    asm("v_mfma_f32_16x16x16_bf16 %0, %1, %2, %0" : "+v"(d) : "v"(a), "v"(b));
}

// async global->LDS, 16B per lane; LDS dest = wave-uniform base + lane*16
#define ASYNC_COPY16(gsrc, ldst) \
    __builtin_amdgcn_global_load_lds((const __attribute__((address_space(1))) void*)(gsrc), \
                                     (__attribute__((address_space(3))) void*)(ldst), 16, 0, 0)

// ---------------- Fused prep: wconv (bid<4096) | LN (bid<8192) | rope tables ----------------
__global__ __launch_bounds__(256) void prep_kernel(const float* __restrict__ Wq,
                                                   const float* __restrict__ Wk,
                                                   const float* __restrict__ Wv,
                                                   const float* __restrict__ Wo,
                                                   u16* __restrict__ wqkvT,
                                                   u16* __restrict__ woT,
                                                   const float* __restrict__ h,
                                                   const float* __restrict__ gamma,
                                                   const float* __restrict__ beta,
                                                   u16* __restrict__ hn,
                                                   float* __restrict__ cosT,
                                                   float* __restrict__ sinT) {
    __shared__ float tile[32][33];
    __shared__ float red[8];
    int bid = blockIdx.x;
    int t = threadIdx.x;
    if (bid < 4096) {
        int z = bid >> 10;
        int rem = bid & 1023;
        const float* W = (z == 0) ? Wq : (z == 1) ? Wk : (z == 2) ? Wv : Wo;
        u16* Wt = (z < 3) ? wqkvT + (size_t)z * DMODEL * DMODEL : woT;
        int bx = (rem & 31) * 32;   // n
        int by = (rem >> 5) * 32;   // k
        int tx = t & 31, ty = t >> 5;
#pragma unroll
        for (int i = 0; i < 32; i += 8)
            tile[ty + i][tx] = W[(size_t)(by + ty + i) * DMODEL + bx + tx];
        __syncthreads();
#pragma unroll
        for (int i = 0; i < 32; i += 8)
            Wt[(size_t)(bx + ty + i) * DMODEL + by + tx] = f2bf(tile[tx][ty + i]);
    } else if (bid < 8192) {
        int row = bid - 4096;
        float4 v = reinterpret_cast<const float4*>(h + (size_t)row * DMODEL)[t];
        float s  = v.x + v.y + v.z + v.w;
        float s2 = v.x*v.x + v.y*v.y + v.z*v.z + v.w*v.w;
#pragma unroll
        for (int off = 1; off < 64; off <<= 1) {
            s  += __shfl_xor(s, off);
            s2 += __shfl_xor(s2, off);
        }
        int wid = t >> 6, lane = t & 63;
        if (lane == 0) { red[wid] = s; red[4 + wid] = s2; }
        __syncthreads();
        s  = red[0] + red[1] + red[2] + red[3];
        s2 = red[4] + red[5] + red[6] + red[7];
        float mu   = s * (1.0f / DMODEL);
        float rstd = rsqrtf(s2 * (1.0f / DMODEL) - mu * mu + 1e-5f);
        float4 g = reinterpret_cast<const float4*>(gamma)[t];
        float4 b = reinterpret_cast<const float4*>(beta)[t];
        ushort4 o;
        o.x = f2bf((v.x - mu) * rstd * g.x + b.x);
        o.y = f2bf((v.y - mu) * rstd * g.y + b.y);
        o.z = f2bf((v.z - mu) * rstd * g.z + b.z);
        o.w = f2bf((v.w - mu) * rstd * g.w + b.w);
        reinterpret_cast<ushort4*>(hn + (size_t)row * DMODEL)[t] = o;
    } else {
        int idx = (bid - 8192) * 256 + t;
        int s = idx >> 5, i = idx & 31;
        float theta = powf(10000.0f, -2.0f * (float)i / 64.0f);
        float ang = (float)s * theta;
        cosT[idx] = cosf(ang);
        sinT[idx] = sinf(ang);
    }
}

// ---------------- GEMM: 128x128 tile, BK=64, global_load_lds double-buffer ----------------
// EPI=0: merged QKV (Bt rows 0..3071). seg=bn>>3: 0=Q (RoPE, *log2e/8 -> o0),
//        1=K (RoPE -> o1), 2=V (write V^T [head][64][seq] -> o2).
// EPI=1: +bias +residual, fp32 [seq][1024] -> ofp.
template <int EPI>
__global__ __launch_bounds__(256) void gemm_kernel(const u16* __restrict__ A,
                                                   const u16* __restrict__ Bt,
                                                   const float* __restrict__ b0,
                                                   const float* __restrict__ b1,
                                                   const float* __restrict__ b2,
                                                   const float* __restrict__ resid,
                                                   const float* __restrict__ cosT,
                                                   const float* __restrict__ sinT,
                                                   u16* __restrict__ o0,
                                                   u16* __restrict__ o1,
                                                   u16* __restrict__ o2,
                                                   float* __restrict__ ofp) {
    __shared__ alignas(16) u16 As[2][128 * 64];
    __shared__ alignas(16) u16 Bs[2][128 * 64];
    int bm = blockIdx.x, bn = blockIdx.y;
    int tid = threadIdx.x;
    int wid = tid >> 6, lane = tid & 63;
    int wm = wid >> 1, wn = wid & 1;
    int t15 = lane & 15, g = lane >> 4;
    const u16* Abase = A  + (size_t)bm * 128 * DMODEL;
    const u16* Bbase = Bt + (size_t)bn * 128 * DMODEL;
    int srow = tid >> 3;          // 0..31 within each 32-row issue chunk
    int sslot = tid & 7;
    f32x4 acc[4][4] = {};

    // LDS[row][slot] = global[row][slot ^ (row&7)]  (slots of 8 elems = 16B)
#define GSTAGE(b, ks)                                                                    \
    {                                                                                    \
        _Pragma("unroll")                                                                \
        for (int i = 0; i < 4; i++) {                                                    \
            int row = i * 32 + srow;                                                     \
            int col = ((sslot ^ (row & 7)) * 8) + (ks);                                  \
            ASYNC_COPY16(Abase + (size_t)row * DMODEL + col, &As[b][i * 2048 + wid * 512]); \
            ASYNC_COPY16(Bbase + (size_t)row * DMODEL + col, &Bs[b][i * 2048 + wid * 512]); \
        }                                                                                \
    }

    GSTAGE(0, 0)
    __syncthreads();
    int buf = 0;
    for (int ks = 0; ks < DMODEL; ks += 64) {
        if (ks < DMODEL - 64) GSTAGE(buf ^ 1, ks + 64)
#pragma unroll
        for (int kk = 0; kk < 2; kk++) {
            i32x4 af[4], bfr[4];
#pragma unroll
            for (int mi = 0; mi < 4; mi++) {
                int row = wm * 64 + mi * 16 + t15;
                int sl = (kk * 4 + g) ^ (row & 7);
                af[mi] = *reinterpret_cast<const i32x4*>(&As[buf][row * 64 + sl * 8]);
            }
#pragma unroll
            for (int ni = 0; ni < 4; ni++) {
                int row = wn * 64 + ni * 16 + t15;
                int sl = (kk * 4 + g) ^ (row & 7);
                bfr[ni] = *reinterpret_cast<const i32x4*>(&Bs[buf][row * 64 + sl * 8]);
            }
            __builtin_amdgcn_s_setprio(1);
#pragma unroll
            for (int mi = 0; mi < 4; mi++)
#pragma unroll
                for (int ni = 0; ni < 4; ni++)
                    mfma_bf16(acc[mi][ni], af[mi], bfr[ni]);
            __builtin_amdgcn_s_setprio(0);
        }
        __syncthreads();
        buf ^= 1;
    }
#undef GSTAGE

    if (EPI == 0) {
        int seg = bn >> 3;                 // 0=Q 1=K 2=V
        int bnl = bn & 7;
        const float* bias = (seg == 0) ? b0 : (seg == 1) ? b1 : b2;
        if (seg < 2) {
            u16* o = (seg == 0) ? o0 : o1;
            float qs = (seg == 0) ? 0.18033688f : 1.0f;   // log2(e)/8 for Q
#pragma unroll
            for (int mi = 0; mi < 4; mi++) {
#pragma unroll
                for (int nl = 0; nl < 2; nl++) {
                    int n10 = bnl * 128 + wn * 64 + nl * 16 + t15;  // d&63 in 0..31
                    int head = n10 >> 6;
                    int dA = n10 & 63, dB = dA + 32;
                    float bvA = bias[n10], bvB = bias[n10 + 32];
#pragma unroll
                    for (int r = 0; r < 4; r++) {
                        int m = bm * 128 + wm * 64 + mi * 16 + g * 4 + r;
                        float c  = cosT[m * 32 + dA];
                        float sn = sinT[m * 32 + dA];
                        float xA = acc[mi][nl][r] + bvA;
                        float xB = acc[mi][nl + 2][r] + bvB;
                        o[(size_t)(head * SEQLEN + m) * DKDIM + dA] = f2bf((xA * c - xB * sn) * qs);
                        o[(size_t)(head * SEQLEN + m) * DKDIM + dB] = f2bf((xB * c + xA * sn) * qs);
                    }
                }
            }
        } else {
#pragma unroll
            for (int mi = 0; mi < 4; mi++) {
#pragma unroll
                for (int ni = 0; ni < 4; ni++) {
                    int n10 = bnl * 128 + wn * 64 + ni * 16 + t15;
                    int head = n10 >> 6, dv = n10 & 63;
                    float bv = bias[n10];
                    int m = bm * 128 + wm * 64 + mi * 16 + g * 4;
                    ushort4 w4;
                    w4.x = f2bf(acc[mi][ni][0] + bv);
                    w4.y = f2bf(acc[mi][ni][1] + bv);
                    w4.z = f2bf(acc[mi][ni][2] + bv);
                    w4.w = f2bf(acc[mi][ni][3] + bv);
                    *reinterpret_cast<ushort4*>(&o2[(size_t)(head * DKDIM + dv) * SEQLEN + m]) = w4;
                }
            }
        }
    } else {
#pragma unroll
        for (int mi = 0; mi < 4; mi++) {
#pragma unroll
            for (int ni = 0; ni < 4; ni++) {
                int n = bn * 128 + wn * 64 + ni * 16 + t15;
                float bv = b0[n];
#pragma unroll
                for (int r = 0; r < 4; r++) {
                    int m = bm * 128 + wm * 64 + mi * 16 + g * 4 + r;
                    ofp[(size_t)m * DMODEL + n] = acc[mi][ni][r] + bv + resid[(size_t)m * DMODEL + n];
                }
            }
        }
    }
}

// ---------------- Flash attention, causal, exp2-domain, defer-max ----------------
// q (pre-scaled by log2e/8), k bf16 [head][seq][64]; vt bf16 [head][64][seq];
// out bf16 [seq][1024]. 512 blocks x 256 threads (4 waves x 32 q-rows, 2 frags
// per wave = 128-row Q tile). One q-tile per block, Q = 31-(bid>>4) so long
// blocks dispatch first -> hardware LPT backfill balances CUs. KVBLK=128
// double-buffered (64KB LDS -> 2 blocks/CU, decorrelated barriers). h=bid&15
// keeps XCD head pinning. No split-K merge (direct epilogue).
__global__ __launch_bounds__(256, 2) void attn_kernel(const u16* __restrict__ q,
                                                      const u16* __restrict__ k,
                                                      const u16* __restrict__ vt,
                                                      u16* __restrict__ o) {
    __shared__ alignas(16) u16 Kl[2][128 * 64];
    __shared__ alignas(16) u16 Vl[2][64 * 128];
    int bid = blockIdx.x;
    int h = bid & 15;                          // XCD-pinned heads
    int Q = 31 - (bid >> 4);                   // longest-first dispatch
    int tid = threadIdx.x;
    int wid = tid >> 6;
    int lane = tid & 63;
    int t15 = lane & 15, g = lane >> 4;
    const u16* Qh  = q  + (size_t)h * SEQLEN * DKDIM;
    const u16* Kh  = k  + (size_t)h * SEQLEN * DKDIM;
    const u16* VtH = vt + (size_t)h * DKDIM * SEQLEN;
    int sslotK = lane & 7;
    int sslotV = lane & 15;

    // lane-constant LDS read bases (u16-element units)
    int c7 = t15 & 7;
    int kc0e = t15 * 64 + ((g ^ c7) << 3);
    int kc1e = t15 * 64 + (((4 + g) ^ c7) << 3);
    int vce[8];
#pragma unroll
    for (int kb = 0; kb < 8; kb++)
        vce[kb] = t15 * 128 + ((((kb * 2) + (g >> 1)) ^ c7) << 3) + ((g & 1) << 2);

    // stage 128-row K tile + 64x128 V^T tile; linear LDS dest, pre-swizzled src
#define STAGE(bb, t_)                                                                   \
    {                                                                                   \
        int k0s = (t_) * 128;                                                           \
        _Pragma("unroll")                                                               \
        for (int it = 0; it < 4; it++) {                                                \
            int u    = wid * 4 + it;                                                    \
            int krow = u * 8 + (lane >> 3);                                             \
            int ksl  = (sslotK ^ (krow & 7)) * 8;                                       \
            ASYNC_COPY16(Kh + (size_t)(k0s + krow) * DKDIM + ksl, &Kl[bb][u * 512]);    \
            int vrow = u * 4 + (lane >> 4);                                             \
            int vsl  = (sslotV ^ (vrow & 7)) * 8;                                       \
            ASYNC_COPY16(VtH + (size_t)vrow * SEQLEN + k0s + vsl, &Vl[bb][u * 512]);    \
        }                                                                               \
    }

    int n = Q + 1;                             // 128-row kv-tiles
    int q0 = Q * 128;
    int qrowA = q0 + wid * 32 + t15;
    int qrowB = qrowA + 16;
    i32x4 qfA0, qfA1, qfB0, qfB1;
    {
        const u16* qp = Qh + (size_t)qrowA * DKDIM + g * 8;
        qfA0 = *reinterpret_cast<const i32x4*>(qp);
        qfA1 = *reinterpret_cast<const i32x4*>(qp + 32);
        const u16* qp2 = qp + 16 * DKDIM;
        qfB0 = *reinterpret_cast<const i32x4*>(qp2);
        qfB1 = *reinterpret_cast<const i32x4*>(qp2 + 32);
    }
    f32x4 oA[4] = {}, oB[4] = {};
    float mA = -1e30f, mB = -1e30f, lA = 0.f, lB = 0.f;

    STAGE(0, 0)
    __syncthreads();
    int buf = 0;
    for (int t = 0; t < n; t++) {
        if (t + 1 < n) STAGE(buf ^ 1, t + 1)
        const u16* Kp0 = Kl[buf] + kc0e;
        const u16* Kp1 = Kl[buf] + kc1e;
        const u16* Vp  = Vl[buf];
        int k0 = t * 128;
        // ---- S^T = K . Q^T for both frags (K-frags read once) ----
        f32x4 sA[8] = {}, sB[8] = {};
        __builtin_amdgcn_s_setprio(1);
#pragma unroll
        for (int kb = 0; kb < 8; kb++) {
            i32x4 kf0 = *reinterpret_cast<const i32x4*>(Kp0 + kb * 1024);
            i32x4 kf1 = *reinterpret_cast<const i32x4*>(Kp1 + kb * 1024);
            mfma_bf16(sA[kb], kf0, qfA0);
            mfma_bf16(sA[kb], kf1, qfA1);
            mfma_bf16(sB[kb], kf0, qfB0);
            mfma_bf16(sB[kb], kf1, qfB1);
        }
        __builtin_amdgcn_s_setprio(0);
        // ---- causal mask: only the diagonal tile (t == Q) ----
        if (t == n - 1) {
#pragma unroll
            for (int kb = 0; kb < 8; kb++)
#pragma unroll
                for (int r = 0; r < 4; r++) {
                    int kvg = k0 + kb * 16 + g * 4 + r;
                    if (kvg > qrowA) sA[kb][r] = -1e30f;
                    if (kvg > qrowB) sB[kb][r] = -1e30f;
                }
        }
        // ---- per-lane tile max (tree) + defer-max (combined) ----
        float amx[8], bmx[8];
#pragma unroll
        for (int kb = 0; kb < 8; kb++) {
            amx[kb] = fmaxf(fmaxf(sA[kb][0], sA[kb][1]), fmaxf(sA[kb][2], sA[kb][3]));
            bmx[kb] = fmaxf(fmaxf(sB[kb][0], sB[kb][1]), fmaxf(sB[kb][2], sB[kb][3]));
        }
        float mxA = fmaxf(fmaxf(fmaxf(amx[0], amx[1]), fmaxf(amx[2], amx[3])),
                          fmaxf(fmaxf(amx[4], amx[5]), fmaxf(amx[6], amx[7])));
        float mxB = fmaxf(fmaxf(fmaxf(bmx[0], bmx[1]), fmaxf(bmx[2], bmx[3])),
                          fmaxf(fmaxf(bmx[4], bmx[5]), fmaxf(bmx[6], bmx[7])));
        if (!__all((mxA <= mA + 8.0f) && (mxB <= mB + 8.0f))) {
            float mrA = fmaxf(mxA, __shfl_xor(mxA, 16));
            mrA = fmaxf(mrA, __shfl_xor(mrA, 32));
            float mnA = fmaxf(mA, mrA);
            float fdA = exp2a(mA - mnA);
            mA = mnA; lA *= fdA;
            oA[0] *= fdA; oA[1] *= fdA; oA[2] *= fdA; oA[3] *= fdA;
            float mrB = fmaxf(mxB, __shfl_xor(mxB, 16));
            mrB = fmaxf(mrB, __shfl_xor(mrB, 32));
            float mnB = fmaxf(mB, mrB);
            float fdB = exp2a(mB - mnB);
            mB = mnB; lB *= fdB;
            oB[0] *= fdB; oB[1] *= fdB; oB[2] *= fdB; oB[3] *= fdB;
        }
        // ---- fused: p = exp2(s-m), pack, PV MFMA per kb ----
        float psA = 0.f, psB = 0.f;
#pragma unroll
        for (int kb = 0; kb < 8; kb++) {
            float pa0 = exp2a(sA[kb][0] - mA);
            float pa1 = exp2a(sA[kb][1] - mA);
            float pa2 = exp2a(sA[kb][2] - mA);
            float pa3 = exp2a(sA[kb][3] - mA);
            psA += (pa0 + pa1) + (pa2 + pa3);
            i32x2 pfA = i32x2{(int)cvtpk(pa0, pa1), (int)cvtpk(pa2, pa3)};
            float pb0 = exp2a(sB[kb][0] - mB);
            float pb1 = exp2a(sB[kb][1] - mB);
            float pb2 = exp2a(sB[kb][2] - mB);
            float pb3 = exp2a(sB[kb][3] - mB);
            psB += (pb0 + pb1) + (pb2 + pb3);
            i32x2 pfB = i32x2{(int)cvtpk(pb0, pb1), (int)cvtpk(pb2, pb3)};
            __builtin_amdgcn_s_setprio(1);
#pragma unroll
            for (int nb = 0; nb < 4; nb++) {
                i32x2 vf = *reinterpret_cast<const i32x2*>(Vp + vce[kb] + nb * 2048);
                mfma16_bf16(oA[nb], vf, pfA);
                mfma16_bf16(oB[nb], vf, pfB);
            }
            __builtin_amdgcn_s_setprio(0);
        }
        lA += psA;
        lB += psB;
        __syncthreads();
        buf ^= 1;
    }
    // ---- reduce l across the 4 k-slot lanes of each q-row; direct write ----
    lA += __shfl_xor(lA, 16); lA += __shfl_xor(lA, 32);
    lB += __shfl_xor(lB, 16); lB += __shfl_xor(lB, 32);
    float invA = 1.0f / lA;
    float invB = 1.0f / lB;
#pragma unroll
    for (int nb = 0; nb < 4; nb++) {
        ushort4 w4;
        w4.x = f2bf(oA[nb][0] * invA);
        w4.y = f2bf(oA[nb][1] * invA);
        w4.z = f2bf(oA[nb][2] * invA);
        w4.w = f2bf(oA[nb][3] * invA);
        *reinterpret_cast<ushort4*>(&o[(size_t)qrowA * DMODEL + h * DKDIM + nb * 16 + g * 4]) = w4;
        w4.x = f2bf(oB[nb][0] * invB);
        w4.y = f2bf(oB[nb][1] * invB);
        w4.z = f2bf(oB[nb][2] * invB);
        w4.w = f2bf(oB[nb][3] * invB);
        *reinterpret_cast<ushort4*>(&o[(size_t)qrowB * DMODEL + h * DKDIM + nb * 16 + g * 4]) = w4;
    }
#undef STAGE
}

extern "C" void kernel_launch(void* const* d_in, const int* in_sizes, int n_in,
                              void* d_out, int out_size, void* d_ws, size_t ws_size,
                              hipStream_t stream) {
    const float* h     = (const float*)d_in[0];
    const float* gamma = (const float*)d_in[1];
    const float* beta  = (const float*)d_in[2];
    const float* Wq    = (const float*)d_in[3];
    const float* bq    = (const float*)d_in[4];
    const float* Wk    = (const float*)d_in[5];
    const float* bk    = (const float*)d_in[6];
    const float* Wv    = (const float*)d_in[7];
    const float* bv    = (const float*)d_in[8];
    const float* Wo    = (const float*)d_in[9];
    const float* bo    = (const float*)d_in[10];
    float* out = (float*)d_out;

    char* ws = (char*)d_ws;
    u16* hn     = (u16*)(ws);                        // 8 MiB; reused as attn output
    u16* wqkvT  = (u16*)(ws + (8ull  << 20));        // 6 MiB [3072][1024]
    u16* woT    = (u16*)(ws + (14ull << 20));        // 2 MiB
    u16* qb     = (u16*)(ws + (16ull << 20));        // [16][4096][64]
    u16* kbuf   = (u16*)(ws + (24ull << 20));        // [16][4096][64]
    u16* vtb    = (u16*)(ws + (32ull << 20));        // [16][64][4096]
    float* cosT = (float*)(ws + (40ull << 20));
    float* sinT = (float*)(ws + (40ull << 20) + (512ull << 10));
    u16* attn = hn;

    prep_kernel<<<8704, 256, 0, stream>>>(Wq, Wk, Wv, Wo, wqkvT, woT,
                                          h, gamma, beta, hn, cosT, sinT);
    gemm_kernel<0><<<dim3(32, 24), 256, 0, stream>>>(hn, wqkvT, bq, bk, bv, nullptr,
                                                     cosT, sinT, qb, kbuf, vtb, nullptr);
    attn_kernel<<<512, 256, 0, stream>>>(qb, kbuf, vtb, attn);
    gemm_kernel<1><<<dim3(32, 8), 256, 0, stream>>>(attn, woT, bo, nullptr, nullptr, h,
                                                    nullptr, nullptr, nullptr, nullptr, nullptr, out);
}

// Round 18
// 131.408 us; speedup vs baseline: 1.2160x; 1.2160x over previous
//
#include <hip/hip_runtime.h>
#include <stdint.h>

#define SEQLEN 4096
#define DMODEL 1024
#define NHEADS 16
#define DKDIM  64

typedef unsigned short u16;
typedef unsigned int   u32;
using f32x4 = __attribute__((ext_vector_type(4))) float;
using i32x4 = __attribute__((ext_vector_type(4))) int;
using i32x2 = __attribute__((ext_vector_type(2))) int;
using u16x8 = __attribute__((ext_vector_type(8))) unsigned short;

__device__ __forceinline__ u16 f2bf(float f) {
    u32 x = __builtin_bit_cast(u32, f);
    u32 r = x + 0x7fffu + ((x >> 16) & 1u);   // RNE
    return (u16)(r >> 16);
}
__device__ __forceinline__ float exp2a(float x) {
    float r; asm("v_exp_f32 %0, %1" : "=v"(r) : "v"(x)); return r;
}
__device__ __forceinline__ u32 cvtpk(float lo, float hi) {
    u32 r; asm("v_cvt_pk_bf16_f32 %0, %1, %2" : "=v"(r) : "v"(lo), "v"(hi)); return r;
}

// 16x16x32: A lane holds A[lane&15][(lane>>4)*8+j]; B: B[(lane>>4)*8+j][lane&15];
// C/D: D[(lane>>4)*4+r][lane&15]
__device__ __forceinline__ void mfma_bf16(f32x4& d, i32x4 a, i32x4 b) {
    asm("v_mfma_f32_16x16x32_bf16 %0, %1, %2, %0" : "+v"(d) : "v"(a), "v"(b));
}
// 16x16x16: A lane holds A[lane&15][(lane>>4)*4+j]; B: B[(lane>>4)*4+j][lane&15]
__device__ __forceinline__ void mfma16_bf16(f32x4& d, i32x2 a, i32x2 b) {
    asm("v_mfma_f32_16x16x16_bf16 %0, %1, %2, %0" : "+v"(d) : "v"(a), "v"(b));
}

// async global->LDS, 16B per lane; LDS dest = wave-uniform base + lane*16
#define ASYNC_COPY16(gsrc, ldst) \
    __builtin_amdgcn_global_load_lds((const __attribute__((address_space(1))) void*)(gsrc), \
                                     (__attribute__((address_space(3))) void*)(ldst), 16, 0, 0)

// ---------------- Fused prep: wconv (bid<4096) | LN (bid<8192) | rope tables ----------------
__global__ __launch_bounds__(256) void prep_kernel(const float* __restrict__ Wq,
                                                   const float* __restrict__ Wk,
                                                   const float* __restrict__ Wv,
                                                   const float* __restrict__ Wo,
                                                   u16* __restrict__ wqkvT,
                                                   u16* __restrict__ woT,
                                                   const float* __restrict__ h,
                                                   const float* __restrict__ gamma,
                                                   const float* __restrict__ beta,
                                                   u16* __restrict__ hn,
                                                   float* __restrict__ cosT,
                                                   float* __restrict__ sinT) {
    __shared__ float tile[32][33];
    __shared__ float red[8];
    int bid = blockIdx.x;
    int t = threadIdx.x;
    if (bid < 4096) {
        int z = bid >> 10;
        int rem = bid & 1023;
        const float* W = (z == 0) ? Wq : (z == 1) ? Wk : (z == 2) ? Wv : Wo;
        u16* Wt = (z < 3) ? wqkvT + (size_t)z * DMODEL * DMODEL : woT;
        int bx = (rem & 31) * 32;   // n
        int by = (rem >> 5) * 32;   // k
        int tx = t & 31, ty = t >> 5;
#pragma unroll
        for (int i = 0; i < 32; i += 8)
            tile[ty + i][tx] = W[(size_t)(by + ty + i) * DMODEL + bx + tx];
        __syncthreads();
#pragma unroll
        for (int i = 0; i < 32; i += 8)
            Wt[(size_t)(bx + ty + i) * DMODEL + by + tx] = f2bf(tile[tx][ty + i]);
    } else if (bid < 8192) {
        int row = bid - 4096;
        float4 v = reinterpret_cast<const float4*>(h + (size_t)row * DMODEL)[t];
        float s  = v.x + v.y + v.z + v.w;
        float s2 = v.x*v.x + v.y*v.y + v.z*v.z + v.w*v.w;
#pragma unroll
        for (int off = 1; off < 64; off <<= 1) {
            s  += __shfl_xor(s, off);
            s2 += __shfl_xor(s2, off);
        }
        int wid = t >> 6, lane = t & 63;
        if (lane == 0) { red[wid] = s; red[4 + wid] = s2; }
        __syncthreads();
        s  = red[0] + red[1] + red[2] + red[3];
        s2 = red[4] + red[5] + red[6] + red[7];
        float mu   = s * (1.0f / DMODEL);
        float rstd = rsqrtf(s2 * (1.0f / DMODEL) - mu * mu + 1e-5f);
        float4 g = reinterpret_cast<const float4*>(gamma)[t];
        float4 b = reinterpret_cast<const float4*>(beta)[t];
        ushort4 o;
        o.x = f2bf((v.x - mu) * rstd * g.x + b.x);
        o.y = f2bf((v.y - mu) * rstd * g.y + b.y);
        o.z = f2bf((v.z - mu) * rstd * g.z + b.z);
        o.w = f2bf((v.w - mu) * rstd * g.w + b.w);
        reinterpret_cast<ushort4*>(hn + (size_t)row * DMODEL)[t] = o;
    } else {
        int idx = (bid - 8192) * 256 + t;
        int s = idx >> 5, i = idx & 31;
        float theta = powf(10000.0f, -2.0f * (float)i / 64.0f);
        float ang = (float)s * theta;
        cosT[idx] = cosf(ang);
        sinT[idx] = sinf(ang);
    }
}

// ---------------- QKV GEMM: 128x128 tile, BK=64, global_load_lds double-buffer ----------------
// Merged QKV (Bt rows 0..3071). seg=bn>>3: 0=Q (RoPE, *log2e/8 -> o0),
// 1=K (RoPE -> o1), 2=V (write V^T [head][64][seq] -> o2).
__global__ __launch_bounds__(256) void gemm_qkv_kernel(const u16* __restrict__ A,
                                                       const u16* __restrict__ Bt,
                                                       const float* __restrict__ b0,
                                                       const float* __restrict__ b1,
                                                       const float* __restrict__ b2,
                                                       const float* __restrict__ cosT,
                                                       const float* __restrict__ sinT,
                                                       u16* __restrict__ o0,
                                                       u16* __restrict__ o1,
                                                       u16* __restrict__ o2) {
    __shared__ alignas(16) u16 As[2][128 * 64];
    __shared__ alignas(16) u16 Bs[2][128 * 64];
    int bm = blockIdx.x, bn = blockIdx.y;
    int tid = threadIdx.x;
    int wid = tid >> 6, lane = tid & 63;
    int wm = wid >> 1, wn = wid & 1;
    int t15 = lane & 15, g = lane >> 4;
    const u16* Abase = A  + (size_t)bm * 128 * DMODEL;
    const u16* Bbase = Bt + (size_t)bn * 128 * DMODEL;
    int srow = tid >> 3;
    int sslot = tid & 7;
    f32x4 acc[4][4] = {};

#define GSTAGE(b, ks)                                                                    \
    {                                                                                    \
        _Pragma("unroll")                                                                \
        for (int i = 0; i < 4; i++) {                                                    \
            int row = i * 32 + srow;                                                     \
            int col = ((sslot ^ (row & 7)) * 8) + (ks);                                  \
            ASYNC_COPY16(Abase + (size_t)row * DMODEL + col, &As[b][i * 2048 + wid * 512]); \
            ASYNC_COPY16(Bbase + (size_t)row * DMODEL + col, &Bs[b][i * 2048 + wid * 512]); \
        }                                                                                \
    }

    GSTAGE(0, 0)
    __syncthreads();
    int buf = 0;
    for (int ks = 0; ks < DMODEL; ks += 64) {
        if (ks < DMODEL - 64) GSTAGE(buf ^ 1, ks + 64)
#pragma unroll
        for (int kk = 0; kk < 2; kk++) {
            i32x4 af[4], bfr[4];
#pragma unroll
            for (int mi = 0; mi < 4; mi++) {
                int row = wm * 64 + mi * 16 + t15;
                int sl = (kk * 4 + g) ^ (row & 7);
                af[mi] = *reinterpret_cast<const i32x4*>(&As[buf][row * 64 + sl * 8]);
            }
#pragma unroll
            for (int ni = 0; ni < 4; ni++) {
                int row = wn * 64 + ni * 16 + t15;
                int sl = (kk * 4 + g) ^ (row & 7);
                bfr[ni] = *reinterpret_cast<const i32x4*>(&Bs[buf][row * 64 + sl * 8]);
            }
            __builtin_amdgcn_s_setprio(1);
#pragma unroll
            for (int mi = 0; mi < 4; mi++)
#pragma unroll
                for (int ni = 0; ni < 4; ni++)
                    mfma_bf16(acc[mi][ni], af[mi], bfr[ni]);
            __builtin_amdgcn_s_setprio(0);
        }
        __syncthreads();
        buf ^= 1;
    }
#undef GSTAGE

    int seg = bn >> 3;                 // 0=Q 1=K 2=V
    int bnl = bn & 7;
    const float* bias = (seg == 0) ? b0 : (seg == 1) ? b1 : b2;
    if (seg < 2) {
        u16* o = (seg == 0) ? o0 : o1;
        float qs = (seg == 0) ? 0.18033688f : 1.0f;   // log2(e)/8 for Q
#pragma unroll
        for (int mi = 0; mi < 4; mi++) {
#pragma unroll
            for (int nl = 0; nl < 2; nl++) {
                int n10 = bnl * 128 + wn * 64 + nl * 16 + t15;  // d&63 in 0..31
                int head = n10 >> 6;
                int dA = n10 & 63, dB = dA + 32;
                float bvA = bias[n10], bvB = bias[n10 + 32];
#pragma unroll
                for (int r = 0; r < 4; r++) {
                    int m = bm * 128 + wm * 64 + mi * 16 + g * 4 + r;
                    float c  = cosT[m * 32 + dA];
                    float sn = sinT[m * 32 + dA];
                    float xA = acc[mi][nl][r] + bvA;
                    float xB = acc[mi][nl + 2][r] + bvB;
                    o[(size_t)(head * SEQLEN + m) * DKDIM + dA] = f2bf((xA * c - xB * sn) * qs);
                    o[(size_t)(head * SEQLEN + m) * DKDIM + dB] = f2bf((xB * c + xA * sn) * qs);
                }
            }
        }
    } else {
#pragma unroll
        for (int mi = 0; mi < 4; mi++) {
#pragma unroll
            for (int ni = 0; ni < 4; ni++) {
                int n10 = bnl * 128 + wn * 64 + ni * 16 + t15;
                int head = n10 >> 6, dv = n10 & 63;
                float bv = bias[n10];
                int m = bm * 128 + wm * 64 + mi * 16 + g * 4;
                ushort4 w4;
                w4.x = f2bf(acc[mi][ni][0] + bv);
                w4.y = f2bf(acc[mi][ni][1] + bv);
                w4.z = f2bf(acc[mi][ni][2] + bv);
                w4.w = f2bf(acc[mi][ni][3] + bv);
                *reinterpret_cast<ushort4*>(&o2[(size_t)(head * DKDIM + dv) * SEQLEN + m]) = w4;
            }
        }
    }
}

// ---------------- O-proj GEMM: 64x128 tile (512 blocks = 2/CU), +bias+resid fp32 ----------------
__global__ __launch_bounds__(256, 2) void gemm_o_kernel(const u16* __restrict__ A,
                                                        const u16* __restrict__ Bt,
                                                        const float* __restrict__ bias,
                                                        const float* __restrict__ resid,
                                                        float* __restrict__ ofp) {
    __shared__ alignas(16) u16 As[2][64 * 64];
    __shared__ alignas(16) u16 Bs[2][128 * 64];
    int bm = blockIdx.x, bn = blockIdx.y;
    int tid = threadIdx.x;
    int wid = tid >> 6, lane = tid & 63;
    int wm = wid >> 1, wn = wid & 1;          // wm: 32-row half, wn: 64-col half
    int t15 = lane & 15, g = lane >> 4;
    const u16* Abase = A  + (size_t)bm * 64 * DMODEL;
    const u16* Bbase = Bt + (size_t)bn * 128 * DMODEL;
    int srow = tid >> 3;          // 0..31
    int sslot = tid & 7;
    f32x4 acc[2][4] = {};

#define GSTAGE_O(b, ks)                                                                  \
    {                                                                                    \
        _Pragma("unroll")                                                                \
        for (int i = 0; i < 2; i++) {                                                    \
            int row = i * 32 + srow;                                                     \
            int col = ((sslot ^ (row & 7)) * 8) + (ks);                                  \
            ASYNC_COPY16(Abase + (size_t)row * DMODEL + col, &As[b][i * 2048 + wid * 512]); \
        }                                                                                \
        _Pragma("unroll")                                                                \
        for (int i = 0; i < 4; i++) {                                                    \
            int row = i * 32 + srow;                                                     \
            int col = ((sslot ^ (row & 7)) * 8) + (ks);                                  \
            ASYNC_COPY16(Bbase + (size_t)row * DMODEL + col, &Bs[b][i * 2048 + wid * 512]); \
        }                                                                                \
    }

    GSTAGE_O(0, 0)
    __syncthreads();
    int buf = 0;
    for (int ks = 0; ks < DMODEL; ks += 64) {
        if (ks < DMODEL - 64) GSTAGE_O(buf ^ 1, ks + 64)
#pragma unroll
        for (int kk = 0; kk < 2; kk++) {
            i32x4 af[2], bfr[4];
#pragma unroll
            for (int mi = 0; mi < 2; mi++) {
                int row = wm * 32 + mi * 16 + t15;
                int sl = (kk * 4 + g) ^ (row & 7);
                af[mi] = *reinterpret_cast<const i32x4*>(&As[buf][row * 64 + sl * 8]);
            }
#pragma unroll
            for (int ni = 0; ni < 4; ni++) {
                int row = wn * 64 + ni * 16 + t15;
                int sl = (kk * 4 + g) ^ (row & 7);
                bfr[ni] = *reinterpret_cast<const i32x4*>(&Bs[buf][row * 64 + sl * 8]);
            }
            __builtin_amdgcn_s_setprio(1);
#pragma unroll
            for (int mi = 0; mi < 2; mi++)
#pragma unroll
                for (int ni = 0; ni < 4; ni++)
                    mfma_bf16(acc[mi][ni], af[mi], bfr[ni]);
            __builtin_amdgcn_s_setprio(0);
        }
        __syncthreads();
        buf ^= 1;
    }
#undef GSTAGE_O

#pragma unroll
    for (int mi = 0; mi < 2; mi++) {
#pragma unroll
        for (int ni = 0; ni < 4; ni++) {
            int n = bn * 128 + wn * 64 + ni * 16 + t15;
            float bv = bias[n];
#pragma unroll
            for (int r = 0; r < 4; r++) {
                int m = bm * 64 + wm * 32 + mi * 16 + g * 4 + r;
                ofp[(size_t)m * DMODEL + n] = acc[mi][ni][r] + bv + resid[(size_t)m * DMODEL + n];
            }
        }
    }
}

// ---------------- Flash attention (r16 verbatim): causal, exp2-domain, defer-max ----------------
// 512-thread block = 2 groups x 4 waves; 32 q-rows/wave (2 frags); KVBLK=128;
// block split-K even/odd; triangle pairing {31-p, p}; XCD head pinning.
__global__ __launch_bounds__(512, 2) void attn_kernel(const u16* __restrict__ q,
                                                      const u16* __restrict__ k,
                                                      const u16* __restrict__ vt,
                                                      u16* __restrict__ o) {
    __shared__ alignas(16) u16 SMEM[65536];   // 128 KB: K 4x16KB | V 4x16KB; merge aliases
    int bid = blockIdx.x;
    int h = bid & 15;                          // XCD-pinned heads
    int p = bid >> 4;                          // 0..15
    int tid = threadIdx.x;
    int grp = tid >> 8;                        // 0/1: kv-chunk group
    int wid = (tid >> 6) & 3;                  // wave within group
    int lane = tid & 63;
    int t15 = lane & 15, g = lane >> 4;
    const u16* Qh  = q  + (size_t)h * SEQLEN * DKDIM;
    const u16* Kh  = k  + (size_t)h * SEQLEN * DKDIM;
    const u16* VtH = vt + (size_t)h * DKDIM * SEQLEN;
    int sslotK = lane & 7;
    int sslotV = lane & 15;
    float* Os  = (float*)SMEM;                              // [2][128][68] fp32 (alias)
    float2* Ml = (float2*)((char*)SMEM + 69632);            // [2][128]

    int c7 = t15 & 7;
    int kc0e = t15 * 64 + ((g ^ c7) << 3);
    int kc1e = t15 * 64 + (((4 + g) ^ c7) << 3);
    int vce[8];
#pragma unroll
    for (int kb = 0; kb < 8; kb++)
        vce[kb] = t15 * 128 + ((((kb * 2) + (g >> 1)) ^ c7) << 3) + ((g & 1) << 2);

#define STAGE(bb, t_)                                                                   \
    {                                                                                   \
        int k0s = (t_) * 128;                                                           \
        u16* Kb = SMEM + (size_t)(grp * 2 + (bb)) * 8192;                               \
        u16* Vb = SMEM + 32768 + (size_t)(grp * 2 + (bb)) * 8192;                       \
        _Pragma("unroll")                                                               \
        for (int it = 0; it < 4; it++) {                                                \
            int u    = wid * 4 + it;                                                    \
            int krow = u * 8 + (lane >> 3);                                             \
            int ksl  = (sslotK ^ (krow & 7)) * 8;                                       \
            ASYNC_COPY16(Kh + (size_t)(k0s + krow) * DKDIM + ksl, Kb + u * 512);        \
            int vrow = u * 4 + (lane >> 4);                                             \
            int vsl  = (sslotV ^ (vrow & 7)) * 8;                                       \
            ASYNC_COPY16(VtH + (size_t)vrow * SEQLEN + k0s + vsl, Vb + u * 512);        \
        }                                                                               \
    }

    for (int pass = 0; pass < 2; pass++) {
        int Q = pass ? p : (31 - p);             // 128-row q-tile index
        int n = Q + 1;                           // 128-row kv-tiles
        int iters = (n + 1) >> 1;                // identical for both groups
        int q0 = Q * 128;
        int qrowA = q0 + wid * 32 + t15;
        int qrowB = qrowA + 16;
        i32x4 qfA0, qfA1, qfB0, qfB1;
        {
            const u16* qp = Qh + (size_t)qrowA * DKDIM + g * 8;
            qfA0 = *reinterpret_cast<const i32x4*>(qp);
            qfA1 = *reinterpret_cast<const i32x4*>(qp + 32);
            const u16* qp2 = qp + 16 * DKDIM;
            qfB0 = *reinterpret_cast<const i32x4*>(qp2);
            qfB1 = *reinterpret_cast<const i32x4*>(qp2 + 32);
        }
        f32x4 oA[4] = {}, oB[4] = {};
        float mA = -1e30f, mB = -1e30f, lA = 0.f, lB = 0.f;

        if (grp < n) STAGE(0, grp)
        __syncthreads();
        for (int i = 0; i < iters; i++) {
            int t = grp + 2 * i;
            bool active = t < n;
            int buf = i & 1;
            if (t + 2 < n) STAGE(buf ^ 1, t + 2)
            if (active) {
                int kbe = (grp * 2 + buf) * 8192;
                const u16* Kp0 = SMEM + kbe + kc0e;
                const u16* Kp1 = SMEM + kbe + kc1e;
                const u16* Vp  = SMEM + 32768 + kbe;
                int k0 = t * 128;
                f32x4 sA[8] = {}, sB[8] = {};
                __builtin_amdgcn_s_setprio(1);
#pragma unroll
                for (int kb = 0; kb < 8; kb++) {
                    i32x4 kf0 = *reinterpret_cast<const i32x4*>(Kp0 + kb * 1024);
                    i32x4 kf1 = *reinterpret_cast<const i32x4*>(Kp1 + kb * 1024);
                    mfma_bf16(sA[kb], kf0, qfA0);
                    mfma_bf16(sA[kb], kf1, qfA1);
                    mfma_bf16(sB[kb], kf0, qfB0);
                    mfma_bf16(sB[kb], kf1, qfB1);
                }
                __builtin_amdgcn_s_setprio(0);
                if (t == n - 1) {
#pragma unroll
                    for (int kb = 0; kb < 8; kb++)
#pragma unroll
                        for (int r = 0; r < 4; r++) {
                            int kvg = k0 + kb * 16 + g * 4 + r;
                            if (kvg > qrowA) sA[kb][r] = -1e30f;
                            if (kvg > qrowB) sB[kb][r] = -1e30f;
                        }
                }
                float amx[8], bmx[8];
#pragma unroll
                for (int kb = 0; kb < 8; kb++) {
                    amx[kb] = fmaxf(fmaxf(sA[kb][0], sA[kb][1]), fmaxf(sA[kb][2], sA[kb][3]));
                    bmx[kb] = fmaxf(fmaxf(sB[kb][0], sB[kb][1]), fmaxf(sB[kb][2], sB[kb][3]));
                }
                float mxA = fmaxf(fmaxf(fmaxf(amx[0], amx[1]), fmaxf(amx[2], amx[3])),
                                  fmaxf(fmaxf(amx[4], amx[5]), fmaxf(amx[6], amx[7])));
                float mxB = fmaxf(fmaxf(fmaxf(bmx[0], bmx[1]), fmaxf(bmx[2], bmx[3])),
                                  fmaxf(fmaxf(bmx[4], bmx[5]), fmaxf(bmx[6], bmx[7])));
                if (!__all((mxA <= mA + 8.0f) && (mxB <= mB + 8.0f))) {
                    float mrA = fmaxf(mxA, __shfl_xor(mxA, 16));
                    mrA = fmaxf(mrA, __shfl_xor(mrA, 32));
                    float mnA = fmaxf(mA, mrA);
                    float fdA = exp2a(mA - mnA);
                    mA = mnA; lA *= fdA;
                    oA[0] *= fdA; oA[1] *= fdA; oA[2] *= fdA; oA[3] *= fdA;
                    float mrB = fmaxf(mxB, __shfl_xor(mxB, 16));
                    mrB = fmaxf(mrB, __shfl_xor(mrB, 32));
                    float mnB = fmaxf(mB, mrB);
                    float fdB = exp2a(mB - mnB);
                    mB = mnB; lB *= fdB;
                    oB[0] *= fdB; oB[1] *= fdB; oB[2] *= fdB; oB[3] *= fdB;
                }
                float psA = 0.f, psB = 0.f;
#pragma unroll
                for (int kb = 0; kb < 8; kb++) {
                    float pa0 = exp2a(sA[kb][0] - mA);
                    float pa1 = exp2a(sA[kb][1] - mA);
                    float pa2 = exp2a(sA[kb][2] - mA);
                    float pa3 = exp2a(sA[kb][3] - mA);
                    psA += (pa0 + pa1) + (pa2 + pa3);
                    i32x2 pfA = i32x2{(int)cvtpk(pa0, pa1), (int)cvtpk(pa2, pa3)};
                    float pb0 = exp2a(sB[kb][0] - mB);
                    float pb1 = exp2a(sB[kb][1] - mB);
                    float pb2 = exp2a(sB[kb][2] - mB);
                    float pb3 = exp2a(sB[kb][3] - mB);
                    psB += (pb0 + pb1) + (pb2 + pb3);
                    i32x2 pfB = i32x2{(int)cvtpk(pb0, pb1), (int)cvtpk(pb2, pb3)};
                    __builtin_amdgcn_s_setprio(1);
#pragma unroll
                    for (int nb = 0; nb < 4; nb++) {
                        i32x2 vf = *reinterpret_cast<const i32x2*>(Vp + vce[kb] + nb * 2048);
                        mfma16_bf16(oA[nb], vf, pfA);
                        mfma16_bf16(oB[nb], vf, pfB);
                    }
                    __builtin_amdgcn_s_setprio(0);
                }
                lA += psA;
                lB += psB;
            }
            __syncthreads();
        }
        lA += __shfl_xor(lA, 16); lA += __shfl_xor(lA, 32);
        lB += __shfl_xor(lB, 16); lB += __shfl_xor(lB, 32);
        int rowA = wid * 32 + t15, rowB = rowA + 16;
#pragma unroll
        for (int nb = 0; nb < 4; nb++) {
            *reinterpret_cast<f32x4*>(&Os[(size_t)(grp * 128 + rowA) * 68 + nb * 16 + g * 4]) = oA[nb];
            *reinterpret_cast<f32x4*>(&Os[(size_t)(grp * 128 + rowB) * 68 + nb * 16 + g * 4]) = oB[nb];
        }
        if (g == 0) {
            Ml[grp * 128 + rowA] = make_float2(mA, lA);
            Ml[grp * 128 + rowB] = make_float2(mB, lB);
        }
        __syncthreads();
        {
            int r = tid >> 2, c4 = tid & 3;
            int d0 = c4 * 16;
            float2 c0 = Ml[r], c1 = Ml[128 + r];
            float M = fmaxf(c0.x, c1.x);
            float w0 = exp2a(c0.x - M), w1 = exp2a(c1.x - M);
            float invL = 1.0f / (w0 * c0.y + w1 * c1.y);
            u16* op = o + (size_t)(q0 + r) * DMODEL + h * DKDIM + d0;
#pragma unroll
            for (int j = 0; j < 2; j++) {
                f32x4 a0 = *reinterpret_cast<const f32x4*>(&Os[(size_t)r * 68 + d0 + j * 8]);
                f32x4 a1 = *reinterpret_cast<const f32x4*>(&Os[(size_t)r * 68 + d0 + j * 8 + 4]);
                f32x4 b0 = *reinterpret_cast<const f32x4*>(&Os[(size_t)(128 + r) * 68 + d0 + j * 8]);
                f32x4 b1 = *reinterpret_cast<const f32x4*>(&Os[(size_t)(128 + r) * 68 + d0 + j * 8 + 4]);
                u16x8 w8;
#pragma unroll
                for (int ii = 0; ii < 4; ii++) {
                    w8[ii]     = f2bf((w0 * a0[ii] + w1 * b0[ii]) * invL);
                    w8[4 + ii] = f2bf((w0 * a1[ii] + w1 * b1[ii]) * invL);
                }
                *reinterpret_cast<u16x8*>(op + j * 8) = w8;
            }
        }
        __syncthreads();
    }
#undef STAGE
}

extern "C" void kernel_launch(void* const* d_in, const int* in_sizes, int n_in,
                              void* d_out, int out_size, void* d_ws, size_t ws_size,
                              hipStream_t stream) {
    const float* h     = (const float*)d_in[0];
    const float* gamma = (const float*)d_in[1];
    const float* beta  = (const float*)d_in[2];
    const float* Wq    = (const float*)d_in[3];
    const float* bq    = (const float*)d_in[4];
    const float* Wk    = (const float*)d_in[5];
    const float* bk    = (const float*)d_in[6];
    const float* Wv    = (const float*)d_in[7];
    const float* bv    = (const float*)d_in[8];
    const float* Wo    = (const float*)d_in[9];
    const float* bo    = (const float*)d_in[10];
    float* out = (float*)d_out;

    char* ws = (char*)d_ws;
    u16* hn     = (u16*)(ws);                        // 8 MiB; reused as attn output
    u16* wqkvT  = (u16*)(ws + (8ull  << 20));        // 6 MiB [3072][1024]
    u16* woT    = (u16*)(ws + (14ull << 20));        // 2 MiB
    u16* qb     = (u16*)(ws + (16ull << 20));        // [16][4096][64]
    u16* kbuf   = (u16*)(ws + (24ull << 20));        // [16][4096][64]
    u16* vtb    = (u16*)(ws + (32ull << 20));        // [16][64][4096]
    float* cosT = (float*)(ws + (40ull << 20));
    float* sinT = (float*)(ws + (40ull << 20) + (512ull << 10));
    u16* attn = hn;

    prep_kernel<<<8704, 256, 0, stream>>>(Wq, Wk, Wv, Wo, wqkvT, woT,
                                          h, gamma, beta, hn, cosT, sinT);
    gemm_qkv_kernel<<<dim3(32, 24), 256, 0, stream>>>(hn, wqkvT, bq, bk, bv,
                                                      cosT, sinT, qb, kbuf, vtb);
    attn_kernel<<<256, 512, 0, stream>>>(qb, kbuf, vtb, attn);
    gemm_o_kernel<<<dim3(64, 8), 256, 0, stream>>>(attn, woT, bo, h, out);
}